// Round 12
// baseline (207.420 us; speedup 1.0000x reference)
//
#include <hip/hip_runtime.h>

constexpr int N  = 100000;
constexpr int E  = 1600000;
constexpr int IN = 128, HID = 64, OUTC = 32;

// coarse radix partition params
constexpr int SHIFT = 9;                       // 512 nodes per bucket
constexpr int NPB   = 1 << SHIFT;              // 512
constexpr int NB    = (N + NPB - 1) / NPB;     // 196 buckets
constexpr int CAP   = 16384;                   // LDS stage cap
constexpr int CAPB  = 9216;                    // fixed bucket stride (mean 8192, +11 sigma)
constexpr int PB    = 800;                     // partition blocks (3 blocks/CU)
constexpr int CHUNK = E / PB;                  // 2000 (exact)

typedef __attribute__((ext_vector_type(8))) short bf16x8_t;  // 8 bf16 (4 VGPR)
typedef __attribute__((ext_vector_type(4))) float f32x4_t;   // 4 fp32

// ---- bf16 helpers ----
__device__ __forceinline__ unsigned short f2bf(float f) {
    union { float f; unsigned int u; } v; v.f = f;
    unsigned int u = v.u;
    return (unsigned short)((u + 0x7fffu + ((u >> 16) & 1u)) >> 16);
}
__device__ __forceinline__ float blo(unsigned u) { return __uint_as_float(u << 16); }
__device__ __forceinline__ float bhi(unsigned u) { return __uint_as_float(u & 0xffff0000u); }

// ---------------- partition edges into FIXED-STRIDE coarse buckets ----------------
// Bucket b owns packed[b*CAPB .. b*CAPB+CAPB); blocks reserve ranges via
// atomicAdd on cursor[b]. dst values staged in LDS once (R11: dst was read
// from global twice -> 6.4 MB redundant traffic + a second latency pass).
__global__ __launch_bounds__(256) void k_part(const int* __restrict__ src,
                                              const int* __restrict__ dst,
                                              int* __restrict__ cursor,
                                              unsigned* __restrict__ packed) {
    __shared__ int lh[NB], lb[NB], lc[NB];     // 2.3 KB
    __shared__ int sdst[CHUNK];                // 8 KB
    const int t = threadIdx.x;
    const int beg = blockIdx.x * CHUNK;
    for (int i = t; i < NB; i += 256) lh[i] = 0;
    __syncthreads();
    for (int i = t; i < CHUNK; i += 256) {     // load dst ONCE + histogram
        int d = dst[beg + i];
        sdst[i] = d;
        atomicAdd(&lh[d >> SHIFT], 1);
    }
    __syncthreads();
    for (int i = t; i < NB; i += 256) {
        lb[i] = lh[i] ? (i * CAPB + atomicAdd(&cursor[i], lh[i])) : 0;
        lc[i] = 0;
    }
    __syncthreads();
    for (int i = t; i < CHUNK; i += 256) {     // dst from LDS, src from global
        int d = sdst[i], b = d >> SHIFT;
        int idx = atomicAdd(&lc[b], 1);
        packed[lb[b] + idx] = ((unsigned)(d & (NPB - 1)) << 17) | (unsigned)src[beg + i];
    }
}

// ---------------- per-bucket CSR build: offs/offsEnd + dinv + in-place sorted csr ----------------
// Prefix scan via wave shuffles (6 shfl_up steps + 2 barriers) instead of the
// 9-step x 2-barrier LDS ladder (18 barriers) — bit-identical scan result.
__global__ __launch_bounds__(512) void k_build(const int* __restrict__ cursor,
                                               unsigned* __restrict__ packed,
                                               int* __restrict__ offs,
                                               int* __restrict__ offsE,
                                               float* __restrict__ dinv) {
    __shared__ int cnt[NPB];
    __shared__ unsigned stage[CAP];            // 64 KB
    __shared__ int wsum[8];
    const int t = threadIdx.x, b = blockIdx.x;
    const int base = b * CAPB, cntE = cursor[b];
    const int node0 = b << SHIFT;
    cnt[t] = 0;
    __syncthreads();
    for (int i = t; i < cntE; i += 512) atomicAdd(&cnt[packed[base + i] >> 17], 1);
    __syncthreads();
    const int v = cnt[t];
    const int lane = t & 63, wv = t >> 6;
    int s = v;                                 // inclusive scan within wave
    #pragma unroll
    for (int off = 1; off < 64; off <<= 1) {
        int x = __shfl_up(s, off, 64);
        if (lane >= off) s += x;
    }
    if (lane == 63) wsum[wv] = s;              // wave totals
    __syncthreads();
    int add = 0;
    #pragma unroll
    for (int w = 0; w < 8; ++w) add += (w < wv) ? wsum[w] : 0;
    s += add;                                  // inclusive scan across block
    const int ex = s - v;                      // exclusive
    const int node = node0 + t;
    if (node < N) {
        offs[node]  = base + ex;
        offsE[node] = base + ex + v;
        dinv[node]  = rsqrtf((float)v + 1.0f); // +1 self loop
    }
    cnt[t] = ex;                               // own slot only; races closed below
    __syncthreads();
    for (int i = t; i < cntE; i += 512) {
        unsigned p = packed[base + i];
        int idx = atomicAdd(&cnt[p >> 17], 1);
        if (idx < CAP) stage[idx] = p & 0x1FFFFu;
    }
    __syncthreads();
    for (int i = t; i < cntE; i += 512)
        packed[base + i] = stage[i];           // in-place: csr == packed buffer
}

// ---------------- GEMM1 via split-bf16 MFMA: Hs = bf16(dinv[row] * (X @ W1)) ----------------
// x = xh + xl, w = wh + wl (bf16 each); X@W ~= xh wh + xl wh + xh wl; fp32 acc.
// 256-thread blocks, ONE 16-row tile per wave -> 6250 independent waves.
__global__ __launch_bounds__(256, 4) void k_gemm1(const float* __restrict__ X,
                                                  const float* __restrict__ W,
                                                  const float* __restrict__ dinv,
                                                  unsigned short* __restrict__ Hs) {
    const int t = threadIdx.x;
    // zero-row (index N) for the padded gathers
    if (blockIdx.x == 0 && t < HID / 2)
        ((unsigned*)(Hs + (size_t)N * HID))[t] = 0u;

    const int wave = t >> 6, l = t & 63;
    const int rlo  = l & 15, khi = l >> 4;     // khi in 0..3
    const int row0 = (blockIdx.x * 4 + wave) * 16;
    if (row0 >= N) return;                     // tail tiles (N % 16 == 0)

    // --- issue A-tile loads first (latency hides under W-prep) ---
    const float* xr = X + (size_t)(row0 + rlo) * IN + khi * 8;
    float4 xa[4], xb[4];
    #pragma unroll
    for (int ks = 0; ks < 4; ++ks) {
        xa[ks] = *(const float4*)(xr + ks * 32);
        xb[ks] = *(const float4*)(xr + ks * 32 + 4);
    }

    // --- W fragments, split hi/lo: 4 k-steps x 4 col-tiles ---
    bf16x8_t wh[4][4], wl[4][4];
    #pragma unroll
    for (int ks = 0; ks < 4; ++ks) {
        #pragma unroll
        for (int ct = 0; ct < 4; ++ct) {
            const float* wp = W + (ks * 32 + khi * 8) * HID + ct * 16 + rlo;
            #pragma unroll
            for (int e = 0; e < 8; ++e) {
                float w = wp[e * HID];
                unsigned short h = f2bf(w);
                float r = w - __uint_as_float((unsigned)h << 16);
                wh[ks][ct][e] = (short)h;
                wl[ks][ct][e] = (short)f2bf(r);
            }
        }
    }

    f32x4_t acc[4] = {{0,0,0,0},{0,0,0,0},{0,0,0,0},{0,0,0,0}};
    #pragma unroll
    for (int ks = 0; ks < 4; ++ks) {
        float xr8[8] = {xa[ks].x, xa[ks].y, xa[ks].z, xa[ks].w,
                        xb[ks].x, xb[ks].y, xb[ks].z, xb[ks].w};
        bf16x8_t ah, al;
        #pragma unroll
        for (int e = 0; e < 8; ++e) {
            unsigned short h = f2bf(xr8[e]);
            ah[e] = (short)h;
            al[e] = (short)f2bf(xr8[e] - __uint_as_float((unsigned)h << 16));
        }
        #pragma unroll
        for (int ct = 0; ct < 4; ++ct)
            acc[ct] = __builtin_amdgcn_mfma_f32_16x16x32_bf16(ah, wh[ks][ct], acc[ct], 0, 0, 0);
        #pragma unroll
        for (int ct = 0; ct < 4; ++ct)
            acc[ct] = __builtin_amdgcn_mfma_f32_16x16x32_bf16(al, wh[ks][ct], acc[ct], 0, 0, 0);
        #pragma unroll
        for (int ct = 0; ct < 4; ++ct)
            acc[ct] = __builtin_amdgcn_mfma_f32_16x16x32_bf16(ah, wl[ks][ct], acc[ct], 0, 0, 0);
    }

    // --- epilogue: scale by dinv, pack bf16, store ---
    const int orow = row0 + khi * 4;
    #pragma unroll
    for (int r = 0; r < 4; ++r) {
        const float d = dinv[orow + r];
        #pragma unroll
        for (int ct = 0; ct < 4; ++ct)
            Hs[(size_t)(orow + r) * HID + ct * 16 + rlo] = f2bf(acc[ct][r] * d);
    }
}

// ---------------- gather1 + fused gemm2 ----------------
// EIGHTH-WAVE per node, uint4 (16B) lanes. W2 staged in LDS (w2s): R10 proved
// W2-from-global queues behind the gather's latency-critical Hs loads in the
// same vmcnt pipe (41->46us). LDS broadcast keeps the global pipe gather-only.
__global__ __launch_bounds__(256) void k_gather1f(const int* __restrict__ offs,
                                                  const int* __restrict__ offsE,
                                                  const int* __restrict__ csr,
                                                  const float* __restrict__ dinv,
                                                  const unsigned short* __restrict__ Hs,
                                                  const float* __restrict__ b1,
                                                  const float* __restrict__ W2,
                                                  unsigned* __restrict__ H2u) {
    __shared__ float w2s[HID * OUTC];          // 8 KB
    __shared__ int   sidx[4][8][100];          // 12.8 KB
    __shared__ float wrow[4][8][68];           // 8.7 KB
    const int t = threadIdx.x;
    // zero-row (index N) of H2u for k_gather2's padded gather
    if (blockIdx.x == 0 && t < OUTC / 2) H2u[(size_t)N * 16 + t] = 0u;
    for (int i = t; i < HID * OUTC / 4; i += 256)
        ((float4*)w2s)[i] = ((const float4*)W2)[i];
    __syncthreads();

    const int wave = t >> 6, lane = t & 63, q = lane >> 3, c = lane & 7;
    const int myNode = blockIdx.x * 32 + wave * 8 + q;     // N % 32 == 0
    const int o0 = offs[myNode], o1 = offsE[myNode];
    const int deg  = o1 - o0;
    const int rdeg = (deg + 7) & ~7;
    for (int i = c; i < deg; i += 8) sidx[wave][q][i] = csr[o0 + i];
    if (c < rdeg - deg) sidx[wave][q][deg + c] = N;        // pad -> zero row

    const uint4* __restrict__ Hu4 = (const uint4*)Hs;      // row = 8 uint4
    const float dn = dinv[myNode];
    uint4 su = Hu4[(size_t)myNode * 8 + c];                // self loop (pre-scaled)
    float p0 = blo(su.x), p1 = bhi(su.x), p2 = blo(su.y), p3 = bhi(su.y);
    float p4 = blo(su.z), p5 = bhi(su.z), p6 = blo(su.w), p7 = bhi(su.w);
    float r0 = 0, r1 = 0, r2 = 0, r3 = 0, r4 = 0, r5 = 0, r6 = 0, r7 = 0;
    for (int k = 0; k < rdeg; k += 8) {
        int4 sa = *(const int4*)&sidx[wave][q][k];         // ds_read_b128
        int4 sb = *(const int4*)&sidx[wave][q][k + 4];     // ds_read_b128
        uint4 u0 = Hu4[(size_t)sa.x * 8 + c];
        uint4 u1 = Hu4[(size_t)sa.y * 8 + c];
        uint4 u2 = Hu4[(size_t)sa.z * 8 + c];
        uint4 u3 = Hu4[(size_t)sa.w * 8 + c];
        uint4 u4 = Hu4[(size_t)sb.x * 8 + c];
        uint4 u5 = Hu4[(size_t)sb.y * 8 + c];
        uint4 u6 = Hu4[(size_t)sb.z * 8 + c];
        uint4 u7 = Hu4[(size_t)sb.w * 8 + c];
        p0 += blo(u0.x); p1 += bhi(u0.x); p2 += blo(u0.y); p3 += bhi(u0.y);
        p4 += blo(u0.z); p5 += bhi(u0.z); p6 += blo(u0.w); p7 += bhi(u0.w);
        r0 += blo(u1.x); r1 += bhi(u1.x); r2 += blo(u1.y); r3 += bhi(u1.y);
        r4 += blo(u1.z); r5 += bhi(u1.z); r6 += blo(u1.w); r7 += bhi(u1.w);
        p0 += blo(u2.x); p1 += bhi(u2.x); p2 += blo(u2.y); p3 += bhi(u2.y);
        p4 += blo(u2.z); p5 += bhi(u2.z); p6 += blo(u2.w); p7 += bhi(u2.w);
        r0 += blo(u3.x); r1 += bhi(u3.x); r2 += blo(u3.y); r3 += bhi(u3.y);
        r4 += blo(u3.z); r5 += bhi(u3.z); r6 += blo(u3.w); r7 += bhi(u3.w);
        p0 += blo(u4.x); p1 += bhi(u4.x); p2 += blo(u4.y); p3 += bhi(u4.y);
        p4 += blo(u4.z); p5 += bhi(u4.z); p6 += blo(u4.w); p7 += bhi(u4.w);
        r0 += blo(u5.x); r1 += bhi(u5.x); r2 += blo(u5.y); r3 += bhi(u5.y);
        r4 += blo(u5.z); r5 += bhi(u5.z); r6 += blo(u5.w); r7 += bhi(u5.w);
        p0 += blo(u6.x); p1 += bhi(u6.x); p2 += blo(u6.y); p3 += bhi(u6.y);
        p4 += blo(u6.z); p5 += bhi(u6.z); p6 += blo(u6.w); p7 += bhi(u6.w);
        r0 += blo(u7.x); r1 += bhi(u7.x); r2 += blo(u7.y); r3 += bhi(u7.y);
        r4 += blo(u7.z); r5 += bhi(u7.z); r6 += blo(u7.w); r7 += bhi(u7.w);
    }
    float s0 = p0 + r0, s1 = p1 + r1, s2 = p2 + r2, s3 = p3 + r3;
    float s4 = p4 + r4, s5 = p5 + r5, s6 = p6 + r6, s7 = p7 + r7;
    float4 ba = *(const float4*)(b1 + 8 * c);
    float4 bbv = *(const float4*)(b1 + 8 * c + 4);
    float4 wv0, wv1;
    wv0.x = fmaxf(s0 * dn + ba.x, 0.0f);                   // fused relu+bias
    wv0.y = fmaxf(s1 * dn + ba.y, 0.0f);
    wv0.z = fmaxf(s2 * dn + ba.z, 0.0f);
    wv0.w = fmaxf(s3 * dn + ba.w, 0.0f);
    wv1.x = fmaxf(s4 * dn + bbv.x, 0.0f);
    wv1.y = fmaxf(s5 * dn + bbv.y, 0.0f);
    wv1.z = fmaxf(s6 * dn + bbv.z, 0.0f);
    wv1.w = fmaxf(s7 * dn + bbv.w, 0.0f);
    *(float4*)&wrow[wave][q][8 * c]     = wv0;
    *(float4*)&wrow[wave][q][8 * c + 4] = wv1;

    // fused gemm2: lane c computes outputs 4c..4c+3 of ITS node (no shuffle);
    // W2 columns from LDS (broadcast, conflict-free)
    float4 acc = {0, 0, 0, 0};
    #pragma unroll
    for (int k = 0; k < HID; k += 4) {
        float4 wr = *(const float4*)&wrow[wave][q][k];
        float4 wa = *(const float4*)&w2s[(k + 0) * OUTC + 4 * c];
        float4 wb = *(const float4*)&w2s[(k + 1) * OUTC + 4 * c];
        float4 wc = *(const float4*)&w2s[(k + 2) * OUTC + 4 * c];
        float4 wd = *(const float4*)&w2s[(k + 3) * OUTC + 4 * c];
        acc.x += wr.x * wa.x + wr.y * wb.x + wr.z * wc.x + wr.w * wd.x;
        acc.y += wr.x * wa.y + wr.y * wb.y + wr.z * wc.y + wr.w * wd.y;
        acc.z += wr.x * wa.z + wr.y * wb.z + wr.z * wc.z + wr.w * wd.z;
        acc.w += wr.x * wa.w + wr.y * wb.w + wr.z * wc.w + wr.w * wd.w;
    }
    uint2 hw;
    hw.x = (unsigned)f2bf(acc.x * dn) | ((unsigned)f2bf(acc.y * dn) << 16);
    hw.y = (unsigned)f2bf(acc.z * dn) | ((unsigned)f2bf(acc.w * dn) << 16);
    ((uint2*)H2u)[(size_t)myNode * 8 + c] = hw;
}

// ---------------- gather2: SIXTEENTH-WAVE per node, uint4 lanes ----------------
__global__ __launch_bounds__(256) void k_gather2(const int* __restrict__ offs,
                                                 const int* __restrict__ offsE,
                                                 const int* __restrict__ csr,
                                                 const float* __restrict__ dinv,
                                                 const unsigned* __restrict__ H2u,
                                                 const float* __restrict__ b2,
                                                 float* __restrict__ out) {
    __shared__ int sidx[4][16][100];           // 25.6 KB
    const int t = threadIdx.x;
    const int wave = t >> 6, lane = t & 63, q = lane >> 2, c = lane & 3;
    const int myNode = blockIdx.x * 64 + wave * 16 + q;    // grid = ceil(N/64)
    if (myNode >= N) return;                   // guard BEFORE staging (tail block)
    const int o0 = offs[myNode], o1 = offsE[myNode];
    const int deg  = o1 - o0;
    const int rdeg = (deg + 7) & ~7;
    for (int i = c; i < deg; i += 4) sidx[wave][q][i] = csr[o0 + i];
    for (int i = deg + c; i < rdeg; i += 4) sidx[wave][q][i] = N;  // pad -> zero row

    const uint4* __restrict__ H4 = (const uint4*)H2u;      // row = 4 uint4
    const float dn = dinv[myNode];
    uint4 su = H4[(size_t)myNode * 4 + c];                 // self loop (pre-scaled)
    float p0 = blo(su.x), p1 = bhi(su.x), p2 = blo(su.y), p3 = bhi(su.y);
    float p4 = blo(su.z), p5 = bhi(su.z), p6 = blo(su.w), p7 = bhi(su.w);
    float r0 = 0, r1 = 0, r2 = 0, r3 = 0, r4 = 0, r5 = 0, r6 = 0, r7 = 0;
    for (int k = 0; k < rdeg; k += 8) {
        int4 sa = *(const int4*)&sidx[wave][q][k];         // ds_read_b128
        int4 sb = *(const int4*)&sidx[wave][q][k + 4];     // ds_read_b128
        uint4 u0 = H4[(size_t)sa.x * 4 + c];
        uint4 u1 = H4[(size_t)sa.y * 4 + c];
        uint4 u2 = H4[(size_t)sa.z * 4 + c];
        uint4 u3 = H4[(size_t)sa.w * 4 + c];
        uint4 u4 = H4[(size_t)sb.x * 4 + c];
        uint4 u5 = H4[(size_t)sb.y * 4 + c];
        uint4 u6 = H4[(size_t)sb.z * 4 + c];
        uint4 u7 = H4[(size_t)sb.w * 4 + c];
        p0 += blo(u0.x); p1 += bhi(u0.x); p2 += blo(u0.y); p3 += bhi(u0.y);
        p4 += blo(u0.z); p5 += bhi(u0.z); p6 += blo(u0.w); p7 += bhi(u0.w);
        r0 += blo(u1.x); r1 += bhi(u1.x); r2 += blo(u1.y); r3 += bhi(u1.y);
        r4 += blo(u1.z); r5 += bhi(u1.z); r6 += blo(u1.w); r7 += bhi(u1.w);
        p0 += blo(u2.x); p1 += bhi(u2.x); p2 += blo(u2.y); p3 += bhi(u2.y);
        p4 += blo(u2.z); p5 += bhi(u2.z); p6 += blo(u2.w); p7 += bhi(u2.w);
        r0 += blo(u3.x); r1 += bhi(u3.x); r2 += blo(u3.y); r3 += bhi(u3.y);
        r4 += blo(u3.z); r5 += bhi(u3.z); r6 += blo(u3.w); r7 += bhi(u3.w);
        p0 += blo(u4.x); p1 += bhi(u4.x); p2 += blo(u4.y); p3 += bhi(u4.y);
        p4 += blo(u4.z); p5 += bhi(u4.z); p6 += blo(u4.w); p7 += bhi(u4.w);
        r0 += blo(u5.x); r1 += bhi(u5.x); r2 += blo(u5.y); r3 += bhi(u5.y);
        r4 += blo(u5.z); r5 += bhi(u5.z); r6 += blo(u5.w); r7 += bhi(u5.w);
        p0 += blo(u6.x); p1 += bhi(u6.x); p2 += blo(u6.y); p3 += bhi(u6.y);
        p4 += blo(u6.z); p5 += bhi(u6.z); p6 += blo(u6.w); p7 += bhi(u6.w);
        r0 += blo(u7.x); r1 += bhi(u7.x); r2 += blo(u7.y); r3 += bhi(u7.y);
        r4 += blo(u7.z); r5 += bhi(u7.z); r6 += blo(u7.w); r7 += bhi(u7.w);
    }
    float s0 = p0 + r0, s1 = p1 + r1, s2 = p2 + r2, s3 = p3 + r3;
    float s4 = p4 + r4, s5 = p5 + r5, s6 = p6 + r6, s7 = p7 + r7;
    float4 ba = *(const float4*)(b2 + 8 * c);
    float4 bbv = *(const float4*)(b2 + 8 * c + 4);
    float4 o0v, o1v;
    o0v.x = s0 * dn + ba.x;  o0v.y = s1 * dn + ba.y;
    o0v.z = s2 * dn + ba.z;  o0v.w = s3 * dn + ba.w;
    o1v.x = s4 * dn + bbv.x; o1v.y = s5 * dn + bbv.y;
    o1v.z = s6 * dn + bbv.z; o1v.w = s7 * dn + bbv.w;
    float* op = out + (size_t)myNode * OUTC + 8 * c;
    *(float4*)op       = o0v;                              // 128B/node, coalesced
    *(float4*)(op + 4) = o1v;
}

extern "C" void kernel_launch(void* const* d_in, const int* in_sizes, int n_in,
                              void* d_out, int out_size, void* d_ws, size_t ws_size,
                              hipStream_t stream) {
    const float* x   = (const float*)d_in[0];
    const int*   ei  = (const int*)d_in[1];
    const float* W1  = (const float*)d_in[2];
    const float* b1  = (const float*)d_in[3];
    const float* W2  = (const float*)d_in[4];
    const float* b2  = (const float*)d_in[5];
    float*       out = (float*)d_out;

    const int* srcp = ei;
    const int* dstp = ei + E;

    char* ws = (char*)d_ws;
    int*            cursor = (int*)(ws + 0);                   // 784 B
    int*            offs   = (int*)(ws + (64u << 10));         // 400 KB
    int*            offsE  = (int*)(ws + (512u << 10));        // 400 KB
    float*          dinv   = (float*)(ws + (960u << 10));      // 400 KB
    unsigned*       packed = (unsigned*)(ws + (1536u << 10));  // 7.23 MB (csr in place)
    unsigned short* Hs     = (unsigned short*)(ws + (9u << 20));   // 12.8 MB + zero row
    unsigned*       H2u    = (unsigned*)(ws + (22u << 20));    // 6.4 MB + zero row
    int*            csr    = (int*)packed;

    hipMemsetAsync(cursor, 0, NB * sizeof(int), stream);
    k_part <<<PB, 256, 0, stream>>>(srcp, dstp, cursor, packed);
    k_build<<<NB, 512, 0, stream>>>(cursor, packed, offs, offsE, dinv);

    k_gemm1   <<<(N / 16 + 3) / 4, 256, 0, stream>>>(x, W1, dinv, Hs);
    k_gather1f<<<N / 32, 256, 0, stream>>>(offs, offsE, csr, dinv, Hs, b1, W2, H2u);
    k_gather2 <<<(N + 63) / 64, 256, 0, stream>>>(offs, offsE, csr, dinv, H2u, b2, out);
}

// Round 13
// 201.796 us; speedup vs baseline: 1.0279x; 1.0279x over previous
//
#include <hip/hip_runtime.h>

constexpr int N  = 100000;
constexpr int E  = 1600000;
constexpr int IN = 128, HID = 64, OUTC = 32;

// coarse radix partition params
constexpr int SHIFT = 9;                       // 512 nodes per bucket
constexpr int NPB   = 1 << SHIFT;              // 512
constexpr int NB    = (N + NPB - 1) / NPB;     // 196 buckets
constexpr int CAP   = 16384;                   // LDS stage cap
constexpr int CAPB  = 9216;                    // fixed bucket stride (mean 8192, +11 sigma)
constexpr int PB    = 800;                     // partition blocks (3 blocks/CU)
constexpr int CHUNK = E / PB;                  // 2000 (exact)

typedef __attribute__((ext_vector_type(8))) short bf16x8_t;  // 8 bf16 (4 VGPR)
typedef __attribute__((ext_vector_type(4))) float f32x4_t;   // 4 fp32

// ---- bf16 helpers ----
__device__ __forceinline__ unsigned short f2bf(float f) {
    union { float f; unsigned int u; } v; v.f = f;
    unsigned int u = v.u;
    return (unsigned short)((u + 0x7fffu + ((u >> 16) & 1u)) >> 16);
}
__device__ __forceinline__ float blo(unsigned u) { return __uint_as_float(u << 16); }
__device__ __forceinline__ float bhi(unsigned u) { return __uint_as_float(u & 0xffff0000u); }

// ---------------- partition edges into FIXED-STRIDE coarse buckets ----------------
__global__ __launch_bounds__(256) void k_part(const int* __restrict__ src,
                                              const int* __restrict__ dst,
                                              int* __restrict__ cursor,
                                              unsigned* __restrict__ packed) {
    __shared__ int lh[NB], lb[NB], lc[NB];     // 2.3 KB
    __shared__ int sdst[CHUNK];                // 8 KB
    const int t = threadIdx.x;
    const int beg = blockIdx.x * CHUNK;
    for (int i = t; i < NB; i += 256) lh[i] = 0;
    __syncthreads();
    for (int i = t; i < CHUNK; i += 256) {     // load dst ONCE + histogram
        int d = dst[beg + i];
        sdst[i] = d;
        atomicAdd(&lh[d >> SHIFT], 1);
    }
    __syncthreads();
    for (int i = t; i < NB; i += 256) {
        lb[i] = lh[i] ? (i * CAPB + atomicAdd(&cursor[i], lh[i])) : 0;
        lc[i] = 0;
    }
    __syncthreads();
    for (int i = t; i < CHUNK; i += 256) {     // dst from LDS, src from global
        int d = sdst[i], b = d >> SHIFT;
        int idx = atomicAdd(&lc[b], 1);
        packed[lb[b] + idx] = ((unsigned)(d & (NPB - 1)) << 17) | (unsigned)src[beg + i];
    }
}

// ---------------- per-bucket CSR build: offs/offsEnd + dinv + in-place sorted csr ----------------
__global__ __launch_bounds__(512) void k_build(const int* __restrict__ cursor,
                                               unsigned* __restrict__ packed,
                                               int* __restrict__ offs,
                                               int* __restrict__ offsE,
                                               float* __restrict__ dinv) {
    __shared__ int cnt[NPB];
    __shared__ unsigned stage[CAP];            // 64 KB
    __shared__ int wsum[8];
    const int t = threadIdx.x, b = blockIdx.x;
    const int base = b * CAPB, cntE = cursor[b];
    const int node0 = b << SHIFT;
    cnt[t] = 0;
    __syncthreads();
    for (int i = t; i < cntE; i += 512) atomicAdd(&cnt[packed[base + i] >> 17], 1);
    __syncthreads();
    const int v = cnt[t];
    const int lane = t & 63, wv = t >> 6;
    int s = v;                                 // inclusive scan within wave
    #pragma unroll
    for (int off = 1; off < 64; off <<= 1) {
        int x = __shfl_up(s, off, 64);
        if (lane >= off) s += x;
    }
    if (lane == 63) wsum[wv] = s;              // wave totals
    __syncthreads();
    int add = 0;
    #pragma unroll
    for (int w = 0; w < 8; ++w) add += (w < wv) ? wsum[w] : 0;
    s += add;                                  // inclusive scan across block
    const int ex = s - v;                      // exclusive
    const int node = node0 + t;
    if (node < N) {
        offs[node]  = base + ex;
        offsE[node] = base + ex + v;
        dinv[node]  = rsqrtf((float)v + 1.0f); // +1 self loop
    }
    cnt[t] = ex;
    __syncthreads();
    for (int i = t; i < cntE; i += 512) {
        unsigned p = packed[base + i];
        int idx = atomicAdd(&cnt[p >> 17], 1);
        if (idx < CAP) stage[idx] = p & 0x1FFFFu;
    }
    __syncthreads();
    for (int i = t; i < cntE; i += 512)
        packed[base + i] = stage[i];           // in-place: csr == packed buffer
}

// ---------------- GEMM1 via split-bf16 MFMA: Hs = bf16(dinv[row] * (X @ W1)) ----------------
// SPILL FIX (R12: co-compile gave gemm1 VGPR=52 -> wh/wl[4][4] spilled to
// scratch, 42.6us, MfmaUtil 4%): W fragments now PREPACKED INTO LDS once per
// block (16KB hi + 16KB lo = 32KB -> 5 blocks/CU). MFMA loop reads each
// fragment via conflict-free ds_read_b128 (lane l reads base + l*16). Split
// math per element identical; MFMA call order identical -> bit-identical Hs.
// Per-thread live state ~90 VGPR of scalars - nothing for the allocator to spill.
__global__ __launch_bounds__(256) void k_gemm1(const float* __restrict__ X,
                                               const float* __restrict__ W,
                                               const float* __restrict__ dinv,
                                               unsigned short* __restrict__ Hs) {
    __shared__ unsigned short whs[16 * 64 * 8];    // 16 KB: frag f=(ks*4+ct)*64+l
    __shared__ unsigned short wls[16 * 64 * 8];    // 16 KB
    const int t = threadIdx.x;
    // zero-row (index N) for the padded gathers
    if (blockIdx.x == 0 && t < HID / 2)
        ((unsigned*)(Hs + (size_t)N * HID))[t] = 0u;

    const int wave = t >> 6, l = t & 63;
    const int rlo  = l & 15, khi = l >> 4;     // khi in 0..3
    const int row0 = (blockIdx.x * 4 + wave) * 16;
    const bool live = row0 < N;                // tail waves still help W-prep

    // --- issue A-tile loads first (latency hides under W-prep) ---
    float4 xa[4], xb[4];
    if (live) {
        const float* xr = X + (size_t)(row0 + rlo) * IN + khi * 8;
        #pragma unroll
        for (int ks = 0; ks < 4; ++ks) {
            xa[ks] = *(const float4*)(xr + ks * 32);
            xb[ks] = *(const float4*)(xr + ks * 32 + 4);
        }
    }

    // --- cooperative W fragment prep: 1024 entries, 4 per thread ---
    for (int f = t; f < 1024; f += 256) {
        const int fl  = f & 63;                // lane slot
        const int fct = (f >> 6) & 3;          // ct
        const int fks = f >> 8;                // ks
        const int fr  = fl & 15, fk = fl >> 4;
        const float* wp = W + (fks * 32 + fk * 8) * HID + fct * 16 + fr;
        #pragma unroll
        for (int e = 0; e < 8; ++e) {
            float w = wp[e * HID];
            unsigned short h = f2bf(w);
            float r = w - __uint_as_float((unsigned)h << 16);
            whs[f * 8 + e] = h;
            wls[f * 8 + e] = f2bf(r);
        }
    }
    __syncthreads();
    if (!live) return;

    f32x4_t acc[4] = {{0,0,0,0},{0,0,0,0},{0,0,0,0},{0,0,0,0}};
    #pragma unroll
    for (int ks = 0; ks < 4; ++ks) {
        float xr8[8] = {xa[ks].x, xa[ks].y, xa[ks].z, xa[ks].w,
                        xb[ks].x, xb[ks].y, xb[ks].z, xb[ks].w};
        bf16x8_t ah, al;
        #pragma unroll
        for (int e = 0; e < 8; ++e) {
            unsigned short h = f2bf(xr8[e]);
            ah[e] = (short)h;
            al[e] = (short)f2bf(xr8[e] - __uint_as_float((unsigned)h << 16));
        }
        bf16x8_t whf[4], wlf[4];
        #pragma unroll
        for (int ct = 0; ct < 4; ++ct)         // 4x ds_read_b128, conflict-free
            whf[ct] = *(const bf16x8_t*)&whs[(((ks * 4 + ct) * 64) + l) * 8];
        #pragma unroll
        for (int ct = 0; ct < 4; ++ct)
            acc[ct] = __builtin_amdgcn_mfma_f32_16x16x32_bf16(ah, whf[ct], acc[ct], 0, 0, 0);
        #pragma unroll
        for (int ct = 0; ct < 4; ++ct)
            acc[ct] = __builtin_amdgcn_mfma_f32_16x16x32_bf16(al, whf[ct], acc[ct], 0, 0, 0);
        #pragma unroll
        for (int ct = 0; ct < 4; ++ct)         // 4x ds_read_b128
            wlf[ct] = *(const bf16x8_t*)&wls[(((ks * 4 + ct) * 64) + l) * 8];
        #pragma unroll
        for (int ct = 0; ct < 4; ++ct)
            acc[ct] = __builtin_amdgcn_mfma_f32_16x16x32_bf16(ah, wlf[ct], acc[ct], 0, 0, 0);
    }

    // --- epilogue: scale by dinv, pack bf16, store ---
    const int orow = row0 + khi * 4;
    #pragma unroll
    for (int r = 0; r < 4; ++r) {
        const float d = dinv[orow + r];
        #pragma unroll
        for (int ct = 0; ct < 4; ++ct)
            Hs[(size_t)(orow + r) * HID + ct * 16 + rlo] = f2bf(acc[ct][r] * d);
    }
}

// ---------------- gather1 + fused gemm2 ----------------
// EIGHTH-WAVE per node, uint4 (16B) lanes. W2 staged in LDS (w2s): R10 proved
// W2-from-global queues behind the gather's latency-critical Hs loads in the
// same vmcnt pipe (41->46us). LDS broadcast keeps the global pipe gather-only.
__global__ __launch_bounds__(256) void k_gather1f(const int* __restrict__ offs,
                                                  const int* __restrict__ offsE,
                                                  const int* __restrict__ csr,
                                                  const float* __restrict__ dinv,
                                                  const unsigned short* __restrict__ Hs,
                                                  const float* __restrict__ b1,
                                                  const float* __restrict__ W2,
                                                  unsigned* __restrict__ H2u) {
    __shared__ float w2s[HID * OUTC];          // 8 KB
    __shared__ int   sidx[4][8][100];          // 12.8 KB
    __shared__ float wrow[4][8][68];           // 8.7 KB
    const int t = threadIdx.x;
    // zero-row (index N) of H2u for k_gather2's padded gather
    if (blockIdx.x == 0 && t < OUTC / 2) H2u[(size_t)N * 16 + t] = 0u;
    for (int i = t; i < HID * OUTC / 4; i += 256)
        ((float4*)w2s)[i] = ((const float4*)W2)[i];
    __syncthreads();

    const int wave = t >> 6, lane = t & 63, q = lane >> 3, c = lane & 7;
    const int myNode = blockIdx.x * 32 + wave * 8 + q;     // N % 32 == 0
    const int o0 = offs[myNode], o1 = offsE[myNode];
    const int deg  = o1 - o0;
    const int rdeg = (deg + 7) & ~7;
    for (int i = c; i < deg; i += 8) sidx[wave][q][i] = csr[o0 + i];
    if (c < rdeg - deg) sidx[wave][q][deg + c] = N;        // pad -> zero row

    const uint4* __restrict__ Hu4 = (const uint4*)Hs;      // row = 8 uint4
    const float dn = dinv[myNode];
    uint4 su = Hu4[(size_t)myNode * 8 + c];                // self loop (pre-scaled)
    float p0 = blo(su.x), p1 = bhi(su.x), p2 = blo(su.y), p3 = bhi(su.y);
    float p4 = blo(su.z), p5 = bhi(su.z), p6 = blo(su.w), p7 = bhi(su.w);
    float r0 = 0, r1 = 0, r2 = 0, r3 = 0, r4 = 0, r5 = 0, r6 = 0, r7 = 0;
    for (int k = 0; k < rdeg; k += 8) {
        int4 sa = *(const int4*)&sidx[wave][q][k];         // ds_read_b128
        int4 sb = *(const int4*)&sidx[wave][q][k + 4];     // ds_read_b128
        uint4 u0 = Hu4[(size_t)sa.x * 8 + c];
        uint4 u1 = Hu4[(size_t)sa.y * 8 + c];
        uint4 u2 = Hu4[(size_t)sa.z * 8 + c];
        uint4 u3 = Hu4[(size_t)sa.w * 8 + c];
        uint4 u4 = Hu4[(size_t)sb.x * 8 + c];
        uint4 u5 = Hu4[(size_t)sb.y * 8 + c];
        uint4 u6 = Hu4[(size_t)sb.z * 8 + c];
        uint4 u7 = Hu4[(size_t)sb.w * 8 + c];
        p0 += blo(u0.x); p1 += bhi(u0.x); p2 += blo(u0.y); p3 += bhi(u0.y);
        p4 += blo(u0.z); p5 += bhi(u0.z); p6 += blo(u0.w); p7 += bhi(u0.w);
        r0 += blo(u1.x); r1 += bhi(u1.x); r2 += blo(u1.y); r3 += bhi(u1.y);
        r4 += blo(u1.z); r5 += bhi(u1.z); r6 += blo(u1.w); r7 += bhi(u1.w);
        p0 += blo(u2.x); p1 += bhi(u2.x); p2 += blo(u2.y); p3 += bhi(u2.y);
        p4 += blo(u2.z); p5 += bhi(u2.z); p6 += blo(u2.w); p7 += bhi(u2.w);
        r0 += blo(u3.x); r1 += bhi(u3.x); r2 += blo(u3.y); r3 += bhi(u3.y);
        r4 += blo(u3.z); r5 += bhi(u3.z); r6 += blo(u3.w); r7 += bhi(u3.w);
        p0 += blo(u4.x); p1 += bhi(u4.x); p2 += blo(u4.y); p3 += bhi(u4.y);
        p4 += blo(u4.z); p5 += bhi(u4.z); p6 += blo(u4.w); p7 += bhi(u4.w);
        r0 += blo(u5.x); r1 += bhi(u5.x); r2 += blo(u5.y); r3 += bhi(u5.y);
        r4 += blo(u5.z); r5 += bhi(u5.z); r6 += blo(u5.w); r7 += bhi(u5.w);
        p0 += blo(u6.x); p1 += bhi(u6.x); p2 += blo(u6.y); p3 += bhi(u6.y);
        p4 += blo(u6.z); p5 += bhi(u6.z); p6 += blo(u6.w); p7 += bhi(u6.w);
        r0 += blo(u7.x); r1 += bhi(u7.x); r2 += blo(u7.y); r3 += bhi(u7.y);
        r4 += blo(u7.z); r5 += bhi(u7.z); r6 += blo(u7.w); r7 += bhi(u7.w);
    }
    float s0 = p0 + r0, s1 = p1 + r1, s2 = p2 + r2, s3 = p3 + r3;
    float s4 = p4 + r4, s5 = p5 + r5, s6 = p6 + r6, s7 = p7 + r7;
    float4 ba = *(const float4*)(b1 + 8 * c);
    float4 bbv = *(const float4*)(b1 + 8 * c + 4);
    float4 wv0, wv1;
    wv0.x = fmaxf(s0 * dn + ba.x, 0.0f);                   // fused relu+bias
    wv0.y = fmaxf(s1 * dn + ba.y, 0.0f);
    wv0.z = fmaxf(s2 * dn + ba.z, 0.0f);
    wv0.w = fmaxf(s3 * dn + ba.w, 0.0f);
    wv1.x = fmaxf(s4 * dn + bbv.x, 0.0f);
    wv1.y = fmaxf(s5 * dn + bbv.y, 0.0f);
    wv1.z = fmaxf(s6 * dn + bbv.z, 0.0f);
    wv1.w = fmaxf(s7 * dn + bbv.w, 0.0f);
    *(float4*)&wrow[wave][q][8 * c]     = wv0;
    *(float4*)&wrow[wave][q][8 * c + 4] = wv1;

    // fused gemm2: lane c computes outputs 4c..4c+3 of ITS node (no shuffle);
    // W2 columns from LDS (broadcast, conflict-free)
    float4 acc = {0, 0, 0, 0};
    #pragma unroll
    for (int k = 0; k < HID; k += 4) {
        float4 wr = *(const float4*)&wrow[wave][q][k];
        float4 wa = *(const float4*)&w2s[(k + 0) * OUTC + 4 * c];
        float4 wb = *(const float4*)&w2s[(k + 1) * OUTC + 4 * c];
        float4 wc = *(const float4*)&w2s[(k + 2) * OUTC + 4 * c];
        float4 wd = *(const float4*)&w2s[(k + 3) * OUTC + 4 * c];
        acc.x += wr.x * wa.x + wr.y * wb.x + wr.z * wc.x + wr.w * wd.x;
        acc.y += wr.x * wa.y + wr.y * wb.y + wr.z * wc.y + wr.w * wd.y;
        acc.z += wr.x * wa.z + wr.y * wb.z + wr.z * wc.z + wr.w * wd.z;
        acc.w += wr.x * wa.w + wr.y * wb.w + wr.z * wc.w + wr.w * wd.w;
    }
    uint2 hw;
    hw.x = (unsigned)f2bf(acc.x * dn) | ((unsigned)f2bf(acc.y * dn) << 16);
    hw.y = (unsigned)f2bf(acc.z * dn) | ((unsigned)f2bf(acc.w * dn) << 16);
    ((uint2*)H2u)[(size_t)myNode * 8 + c] = hw;
}

// ---------------- gather2: SIXTEENTH-WAVE per node, uint4 lanes ----------------
__global__ __launch_bounds__(256) void k_gather2(const int* __restrict__ offs,
                                                 const int* __restrict__ offsE,
                                                 const int* __restrict__ csr,
                                                 const float* __restrict__ dinv,
                                                 const unsigned* __restrict__ H2u,
                                                 const float* __restrict__ b2,
                                                 float* __restrict__ out) {
    __shared__ int sidx[4][16][100];           // 25.6 KB
    const int t = threadIdx.x;
    const int wave = t >> 6, lane = t & 63, q = lane >> 2, c = lane & 3;
    const int myNode = blockIdx.x * 64 + wave * 16 + q;    // grid = ceil(N/64)
    if (myNode >= N) return;                   // guard BEFORE staging (tail block)
    const int o0 = offs[myNode], o1 = offsE[myNode];
    const int deg  = o1 - o0;
    const int rdeg = (deg + 7) & ~7;
    for (int i = c; i < deg; i += 4) sidx[wave][q][i] = csr[o0 + i];
    for (int i = deg + c; i < rdeg; i += 4) sidx[wave][q][i] = N;  // pad -> zero row

    const uint4* __restrict__ H4 = (const uint4*)H2u;      // row = 4 uint4
    const float dn = dinv[myNode];
    uint4 su = H4[(size_t)myNode * 4 + c];                 // self loop (pre-scaled)
    float p0 = blo(su.x), p1 = bhi(su.x), p2 = blo(su.y), p3 = bhi(su.y);
    float p4 = blo(su.z), p5 = bhi(su.z), p6 = blo(su.w), p7 = bhi(su.w);
    float r0 = 0, r1 = 0, r2 = 0, r3 = 0, r4 = 0, r5 = 0, r6 = 0, r7 = 0;
    for (int k = 0; k < rdeg; k += 8) {
        int4 sa = *(const int4*)&sidx[wave][q][k];         // ds_read_b128
        int4 sb = *(const int4*)&sidx[wave][q][k + 4];     // ds_read_b128
        uint4 u0 = H4[(size_t)sa.x * 4 + c];
        uint4 u1 = H4[(size_t)sa.y * 4 + c];
        uint4 u2 = H4[(size_t)sa.z * 4 + c];
        uint4 u3 = H4[(size_t)sa.w * 4 + c];
        uint4 u4 = H4[(size_t)sb.x * 4 + c];
        uint4 u5 = H4[(size_t)sb.y * 4 + c];
        uint4 u6 = H4[(size_t)sb.z * 4 + c];
        uint4 u7 = H4[(size_t)sb.w * 4 + c];
        p0 += blo(u0.x); p1 += bhi(u0.x); p2 += blo(u0.y); p3 += bhi(u0.y);
        p4 += blo(u0.z); p5 += bhi(u0.z); p6 += blo(u0.w); p7 += bhi(u0.w);
        r0 += blo(u1.x); r1 += bhi(u1.x); r2 += blo(u1.y); r3 += bhi(u1.y);
        r4 += blo(u1.z); r5 += bhi(u1.z); r6 += blo(u1.w); r7 += bhi(u1.w);
        p0 += blo(u2.x); p1 += bhi(u2.x); p2 += blo(u2.y); p3 += bhi(u2.y);
        p4 += blo(u2.z); p5 += bhi(u2.z); p6 += blo(u2.w); p7 += bhi(u2.w);
        r0 += blo(u3.x); r1 += bhi(u3.x); r2 += blo(u3.y); r3 += bhi(u3.y);
        r4 += blo(u3.z); r5 += bhi(u3.z); r6 += blo(u3.w); r7 += bhi(u3.w);
        p0 += blo(u4.x); p1 += bhi(u4.x); p2 += blo(u4.y); p3 += bhi(u4.y);
        p4 += blo(u4.z); p5 += bhi(u4.z); p6 += blo(u4.w); p7 += bhi(u4.w);
        r0 += blo(u5.x); r1 += bhi(u5.x); r2 += blo(u5.y); r3 += bhi(u5.y);
        r4 += blo(u5.z); r5 += bhi(u5.z); r6 += blo(u5.w); r7 += bhi(u5.w);
        p0 += blo(u6.x); p1 += bhi(u6.x); p2 += blo(u6.y); p3 += bhi(u6.y);
        p4 += blo(u6.z); p5 += bhi(u6.z); p6 += blo(u6.w); p7 += bhi(u6.w);
        r0 += blo(u7.x); r1 += bhi(u7.x); r2 += blo(u7.y); r3 += bhi(u7.y);
        r4 += blo(u7.z); r5 += bhi(u7.z); r6 += blo(u7.w); r7 += bhi(u7.w);
    }
    float s0 = p0 + r0, s1 = p1 + r1, s2 = p2 + r2, s3 = p3 + r3;
    float s4 = p4 + r4, s5 = p5 + r5, s6 = p6 + r6, s7 = p7 + r7;
    float4 ba = *(const float4*)(b2 + 8 * c);
    float4 bbv = *(const float4*)(b2 + 8 * c + 4);
    float4 o0v, o1v;
    o0v.x = s0 * dn + ba.x;  o0v.y = s1 * dn + ba.y;
    o0v.z = s2 * dn + ba.z;  o0v.w = s3 * dn + ba.w;
    o1v.x = s4 * dn + bbv.x; o1v.y = s5 * dn + bbv.y;
    o1v.z = s6 * dn + bbv.z; o1v.w = s7 * dn + bbv.w;
    float* op = out + (size_t)myNode * OUTC + 8 * c;
    *(float4*)op       = o0v;                              // 128B/node, coalesced
    *(float4*)(op + 4) = o1v;
}

extern "C" void kernel_launch(void* const* d_in, const int* in_sizes, int n_in,
                              void* d_out, int out_size, void* d_ws, size_t ws_size,
                              hipStream_t stream) {
    const float* x   = (const float*)d_in[0];
    const int*   ei  = (const int*)d_in[1];
    const float* W1  = (const float*)d_in[2];
    const float* b1  = (const float*)d_in[3];
    const float* W2  = (const float*)d_in[4];
    const float* b2  = (const float*)d_in[5];
    float*       out = (float*)d_out;

    const int* srcp = ei;
    const int* dstp = ei + E;

    char* ws = (char*)d_ws;
    int*            cursor = (int*)(ws + 0);                   // 784 B
    int*            offs   = (int*)(ws + (64u << 10));         // 400 KB
    int*            offsE  = (int*)(ws + (512u << 10));        // 400 KB
    float*          dinv   = (float*)(ws + (960u << 10));      // 400 KB
    unsigned*       packed = (unsigned*)(ws + (1536u << 10));  // 7.23 MB (csr in place)
    unsigned short* Hs     = (unsigned short*)(ws + (9u << 20));   // 12.8 MB + zero row
    unsigned*       H2u    = (unsigned*)(ws + (22u << 20));    // 6.4 MB + zero row
    int*            csr    = (int*)packed;

    hipMemsetAsync(cursor, 0, NB * sizeof(int), stream);
    k_part <<<PB, 256, 0, stream>>>(srcp, dstp, cursor, packed);
    k_build<<<NB, 512, 0, stream>>>(cursor, packed, offs, offsE, dinv);

    k_gemm1   <<<(N / 16 + 3) / 4, 256, 0, stream>>>(x, W1, dinv, Hs);
    k_gather1f<<<N / 32, 256, 0, stream>>>(offs, offsE, csr, dinv, Hs, b1, W2, H2u);
    k_gather2 <<<(N + 63) / 64, 256, 0, stream>>>(offs, offsE, csr, dinv, H2u, b2, out);
}